// Round 1
// baseline (522.846 us; speedup 1.0000x reference)
//
#include <hip/hip_runtime.h>
#include <math.h>

// DIN-style sequence attention, R6.
// R5 -> R6: counters showed latency-bound (MfmaUtil 5.8, VALUBusy 21.5, HBM 24%,
// Occ 31%). Levers: (1) __launch_bounds__(256,4) — VGPR 84 permits 4 waves/SIMD,
// LDS 25KB*4=100KB fits; was artificially capped at 3. (2) 1-deep software
// prefetch of the next M-tile's keys in Phase B (+16 VGPR, hides ~900cy HBM
// latency under tile compute). (3) prep_weights merged into prep_qpart (one
// launch fewer in the graph).

constexpr int BATCH = 4096;
constexpr int T  = 200;
constexpr int H  = 64;     // D_IN = 4H = 256
constexpr int D1 = 80;
constexpr int D2 = 40;
constexpr int MROW = 208;  // 13 M-tiles of 16
constexpr int KS2 = 104;   // sH1 row stride (96+8 pad)

// ws layout (bytes)
constexpr size_t WS_B1  = 0;          // 20 frags * 64 lanes * 16B = 20480
constexpr size_t WS_B2  = 20480;      // 9 frags * 64 lanes * 16B = 9216
constexpr size_t WS_B2V = 29696;      // 48 floats
constexpr size_t WS_WDV = 29888;      // 48 floats
constexpr size_t WS_QP  = 32768;      // 4096*80 floats
constexpr size_t WS_TOTAL = WS_QP + (size_t)BATCH * D1 * 4;

typedef __attribute__((ext_vector_type(8))) __bf16 bf16x8;
typedef __attribute__((ext_vector_type(4))) float  floatx4;

__device__ __forceinline__ float fsig(float x) {
    return __builtin_amdgcn_rcpf(1.0f + __expf(-x));
}
#define MFMA16(a, b, c) __builtin_amdgcn_mfma_f32_16x16x32_bf16((a), (b), (c), 0, 0, 0)

// ---- fragment-ordered bf16 weights (batch-independent), shared body ----
// B1 covers K=128: k<64 -> W1b-W1c ; k>=64 -> W1d row (k-64).
// frag f = n*4+ks; lane (col=lane&15, quad=lane>>4) holds
// B[k=ks*32+quad*8+e][n*16+col].
__device__ __forceinline__ void prep_weights_body(
    int gid, int gstride,
    const float* __restrict__ W1, const float* __restrict__ W2g,
    const float* __restrict__ b2g, const float* __restrict__ Wdg,
    __bf16* __restrict__ wsB1, __bf16* __restrict__ wsB2,
    float* __restrict__ wsB2v, float* __restrict__ wsWdv)
{
    for (int u = gid; u < 20 * 64; u += gstride) {
        const int f = u >> 6, lane = u & 63;
        const int n = f >> 2, ks = f & 3;
        const int col = lane & 15, quad = lane >> 4;
        const int j = n * 16 + col;
        __bf16 frag[8];
        #pragma unroll
        for (int e = 0; e < 8; ++e) {
            const int kk = ks * 32 + quad * 8 + e;
            const float v = (kk < 64)
                ? (W1[(64 + kk) * D1 + j] - W1[(128 + kk) * D1 + j])
                : W1[(128 + kk) * D1 + j];          // (192+(kk-64)) == 128+kk
            frag[e] = (__bf16)v;
        }
        *(bf16x8*)&wsB1[u * 8] = *(bf16x8*)frag;
    }
    for (int u = gid; u < 9 * 64; u += gstride) {
        const int f = u >> 6, lane = u & 63;
        const int n3 = f / 3, ks3 = f % 3;
        const int col = lane & 15, quad = lane >> 4;
        const int j = n3 * 16 + col;
        __bf16 frag[8];
        #pragma unroll
        for (int e = 0; e < 8; ++e) {
            const int kk = ks3 * 32 + quad * 8 + e;
            frag[e] = (j < D2 && kk < D1) ? (__bf16)W2g[kk * D2 + j] : (__bf16)0.f;
        }
        *(bf16x8*)&wsB2[u * 8] = *(bf16x8*)frag;
    }
    if (gid < 48) {
        wsB2v[gid] = (gid < D2) ? b2g[gid] : 0.f;
        wsWdv[gid] = (gid < D2) ? Wdg[gid] : 0.f;
    }
}

// fallback-path standalone weights kernel (ws too small for qpart)
__global__ void prep_weights(const float* __restrict__ W1,
                             const float* __restrict__ W2g,
                             const float* __restrict__ b2g,
                             const float* __restrict__ Wdg,
                             __bf16* __restrict__ wsB1, __bf16* __restrict__ wsB2,
                             float* __restrict__ wsB2v, float* __restrict__ wsWdv)
{
    const int gid = blockIdx.x * 256 + threadIdx.x;
    const int gstride = gridDim.x * 256;
    prep_weights_body(gid, gstride, W1, W2g, b2g, Wdg, wsB1, wsB2, wsB2v, wsWdv);
}

// ---- merged prep: weights (grid-stride) + qpart[b][j] = b1[j] + q_b.(W1a+W1c) ----
__global__ __launch_bounds__(256) void prep_all(
    const float* __restrict__ q_g, const float* __restrict__ W1,
    const float* __restrict__ b1g, const float* __restrict__ W2g,
    const float* __restrict__ b2g, const float* __restrict__ Wdg,
    __bf16* __restrict__ wsB1, __bf16* __restrict__ wsB2,
    float* __restrict__ wsB2v, float* __restrict__ wsWdv,
    float* __restrict__ wsQp)
{
    __shared__ float sW1s[H * D1];   // 20 KB
    __shared__ float sq[16 * H];     // 4 KB
    const int tid = threadIdx.x;
    const int gid = blockIdx.x * 256 + tid;
    const int gstride = gridDim.x * 256;
    prep_weights_body(gid, gstride, W1, W2g, b2g, Wdg, wsB1, wsB2, wsB2v, wsWdv);

    const int b0 = blockIdx.x * 16;
    for (int idx = tid; idx < H * D1; idx += 256) {
        const int i = idx / D1, j = idx % D1;
        sW1s[idx] = W1[i * D1 + j] + W1[(128 + i) * D1 + j];
    }
    for (int idx = tid; idx < 16 * H; idx += 256)
        sq[idx] = q_g[(size_t)b0 * H + idx];
    __syncthreads();
    for (int idx = tid; idx < 16 * D1; idx += 256) {
        const int bl = idx / D1, j = idx % D1;
        float acc = b1g[j];
        #pragma unroll 8
        for (int i = 0; i < H; ++i)
            acc += sq[bl * H + i] * sW1s[i * D1 + j];
        wsQp[(size_t)(b0 + bl) * D1 + j] = acc;
    }
}

// ---- main ----
template<bool QWS>
__global__ __launch_bounds__(256, 4) void din_main6(
    const float* __restrict__ q_g, const float* __restrict__ keys_g,
    const int* __restrict__ len_g, const float* __restrict__ W1,
    const float* __restrict__ b1g,
    const __bf16* __restrict__ wsB1, const __bf16* __restrict__ wsB2,
    const float* __restrict__ wsB2v, const float* __restrict__ wsWdv,
    const float* __restrict__ wsQp, float* __restrict__ out)
{
    __shared__ __align__(16) __bf16 sB2f[9 * 64 * 8];     // 9.2 KB frag-ordered
    __shared__ __align__(16) __bf16 sH1[4][16][KS2];      // 13.3 KB per-wave H1
    __shared__ __align__(16) float sS[MROW];
    __shared__ __align__(16) float sQp[D1];
    __shared__ __align__(16) float sQ[H];                 // fallback only
    __shared__ __align__(16) float sRed[8];
    __shared__ __align__(16) float sPart[4][H];

    const int b    = blockIdx.x;
    const int tid  = threadIdx.x;
    const int lane = tid & 63;
    const int wave = tid >> 6;
    const int quad = lane >> 4;
    const int col  = lane & 15;
    const int len  = len_g[b];
    const float* __restrict__ qrow  = q_g + (size_t)b * H;
    const float* __restrict__ kbase = keys_g + (size_t)b * T * H;

    // ---- stage B2 frags -> LDS (coalesced float4 copy) ----
    {
        const float4* src = (const float4*)wsB2;
        float4* dst = (float4*)sB2f;
        for (int idx = tid; idx < 9 * 64; idx += 256) dst[idx] = src[idx];
    }
    if (QWS) { if (tid < D1) sQp[tid] = wsQp[(size_t)b * D1 + tid]; }
    else     { if (tid < H)  sQ[tid]  = qrow[tid]; }

    // per-lane q values for the q*k fragments (quad-broadcast loads)
    const float4 qa0 = *(const float4*)(qrow + quad * 8);
    const float4 qa1 = *(const float4*)(qrow + quad * 8 + 4);
    const float4 qb0 = *(const float4*)(qrow + 32 + quad * 8);
    const float4 qb1 = *(const float4*)(qrow + 32 + quad * 8 + 4);
    float qv[16] = {qa0.x, qa0.y, qa0.z, qa0.w, qa1.x, qa1.y, qa1.z, qa1.w,
                    qb0.x, qb0.y, qb0.z, qb0.w, qb1.x, qb1.y, qb1.z, qb1.w};

    // per-lane layer-2 epilogue constants + qpart values
    float b2v[3], wdv[3], qpv[5];
    #pragma unroll
    for (int n = 0; n < 3; ++n) {
        b2v[n] = wsB2v[n * 16 + col];
        wdv[n] = wsWdv[n * 16 + col];
    }

    // B1 fragments resident in VGPRs (20 x 16B/lane, coalesced, L2-broadcast)
    bf16x8 B1f[20];
    #pragma unroll
    for (int f = 0; f < 20; ++f) B1f[f] = *(const bf16x8*)&wsB1[(f * 64 + lane) * 8];

    // zero own wave's sH1 pad cols 80..95 (wave-local, no barrier needed)
    {
        ushort4 z = {0, 0, 0, 0};
        *(ushort4*)&sH1[wave][lane >> 2][80 + (lane & 3) * 4] = z;
    }
    __syncthreads();   // sB2f + sQp (+ sQ) visible

    if (!QWS) {        // inline qpart fallback (ws too small)
        if (tid < D1) {
            float qp = b1g[tid];
            #pragma unroll 8
            for (int i = 0; i < H; ++i)
                qp += sQ[i] * (W1[i * D1 + tid] + W1[(128 + i) * D1 + tid]);
            sQp[tid] = qp;
        }
        __syncthreads();
    }
    #pragma unroll
    for (int n = 0; n < 5; ++n) qpv[n] = sQp[n * 16 + col];

    // ---- Phase B: MFMA scorer; waves stream, no barriers ----
    // 1-deep prefetch: issue next tile's 4x float4 before computing current.
    float4 c0, c1, c2, c3;
    {
        const int rowc = min(wave * 16 + col, T - 1);
        const float* kp = kbase + (size_t)rowc * H + quad * 8;
        c0 = *(const float4*)(kp);
        c1 = *(const float4*)(kp + 4);
        c2 = *(const float4*)(kp + 32);
        c3 = *(const float4*)(kp + 36);
    }
    for (int mt = wave; mt < 13; mt += 4) {
        const int Mb = mt * 16;
        float4 p0 = c0, p1 = c1, p2 = c2, p3 = c3;
        const int mtn = mt + 4;
        if (mtn < 13) {                              // wave-uniform branch
            const int rowc = min(mtn * 16 + col, T - 1);
            const float* kp = kbase + (size_t)rowc * H + quad * 8;
            p0 = *(const float4*)(kp);
            p1 = *(const float4*)(kp + 4);
            p2 = *(const float4*)(kp + 32);
            p3 = *(const float4*)(kp + 36);
        }
        const float kf[16] = {c0.x, c0.y, c0.z, c0.w, c1.x, c1.y, c1.z, c1.w,
                              c2.x, c2.y, c2.z, c2.w, c3.x, c3.y, c3.z, c3.w};
        bf16x8 A0, A1, A2, A3;
        #pragma unroll
        for (int e = 0; e < 8; ++e) {
            A0[e] = (__bf16)kf[e];
            A1[e] = (__bf16)kf[8 + e];
            A2[e] = (__bf16)(qv[e] * kf[e]);          // q*k, k segment 0..31
            A3[e] = (__bf16)(qv[8 + e] * kf[8 + e]);  // q*k, k segment 32..63
        }
        // layer 1: S1 = [k, q*k][16x128] @ W1eff[128x80]
        #pragma unroll
        for (int n = 0; n < 5; ++n) {
            floatx4 acc = {0.f, 0.f, 0.f, 0.f};
            acc = MFMA16(A0, B1f[n * 4 + 0], acc);
            acc = MFMA16(A1, B1f[n * 4 + 1], acc);
            acc = MFMA16(A2, B1f[n * 4 + 2], acc);
            acc = MFMA16(A3, B1f[n * 4 + 3], acc);
            const float qpn = qpv[n];
            #pragma unroll
            for (int r = 0; r < 4; ++r)               // C/D: row=quad*4+r, col
                sH1[wave][quad * 4 + r][n * 16 + col] = (__bf16)fsig(acc[r] + qpn);
        }
        // layer 2: S2 = H1[16x80] @ W2[80x40]; A from own wave's LDS tile
        const bf16x8 C0 = *(const bf16x8*)&sH1[wave][col][quad * 8];
        const bf16x8 C1 = *(const bf16x8*)&sH1[wave][col][32 + quad * 8];
        const bf16x8 C2 = *(const bf16x8*)&sH1[wave][col][64 + quad * 8];
        float sp0 = 0.f, sp1 = 0.f, sp2 = 0.f, sp3 = 0.f;
        #pragma unroll
        for (int n = 0; n < 3; ++n) {
            floatx4 acc = {0.f, 0.f, 0.f, 0.f};
            #pragma unroll
            for (int ks = 0; ks < 3; ++ks) {          // B2 frags from LDS
                const bf16x8 Bf = *(const bf16x8*)&sB2f[((n * 3 + ks) * 64 + lane) * 8];
                acc = MFMA16(ks == 0 ? C0 : (ks == 1 ? C1 : C2), Bf, acc);
            }
            sp0 += fsig(acc[0] + b2v[n]) * wdv[n];
            sp1 += fsig(acc[1] + b2v[n]) * wdv[n];
            sp2 += fsig(acc[2] + b2v[n]) * wdv[n];
            sp3 += fsig(acc[3] + b2v[n]) * wdv[n];
        }
        #pragma unroll
        for (int off = 1; off <= 8; off <<= 1) {      // reduce 16 cols in quad-group
            sp0 += __shfl_xor(sp0, off, 64);
            sp1 += __shfl_xor(sp1, off, 64);
            sp2 += __shfl_xor(sp2, off, 64);
            sp3 += __shfl_xor(sp3, off, 64);
        }
        if (col == 0) {
            sS[Mb + quad * 4 + 0] = sp0;
            sS[Mb + quad * 4 + 1] = sp1;
            sS[Mb + quad * 4 + 2] = sp2;
            sS[Mb + quad * 4 + 3] = sp3;
        }
        c0 = p0; c1 = p1; c2 = p2; c3 = p3;
    }
    __syncthreads();

    // ---- Phase C: block softmax over T (mask t>=len, scale 1/8) ----
    const int t = tid;
    float score = -INFINITY;
    if (t < T && t < len) score = sS[t] * 0.125f;
    float m = score;
    #pragma unroll
    for (int off = 32; off >= 1; off >>= 1)
        m = fmaxf(m, __shfl_xor(m, off, 64));
    if (lane == 0) sRed[wave] = m;
    __syncthreads();
    m = fmaxf(fmaxf(sRed[0], sRed[1]), fmaxf(sRed[2], sRed[3]));

    float e = 0.0f;
    if (t < T && t < len) e = __expf(score - m);
    float l = e;
    #pragma unroll
    for (int off = 32; off >= 1; off >>= 1)
        l += __shfl_xor(l, off, 64);
    if (lane == 0) sRed[4 + wave] = l;
    if (t < T) sS[t] = e;     // own slot: raw score already consumed here
    __syncthreads();
    l = sRed[4] + sRed[5] + sRed[6] + sRed[7];
    const float inv_l = __builtin_amdgcn_rcpf(l);

    // ---- Phase D: out[b][h] = sum_t w_t * K[t][h] (global fp32, L2-hot) ----
    const int h = tid & 63;
    const int c = tid >> 6;                            // 4 chunks of 50
    float p = 0.0f;
    for (int t2 = c * 50; t2 < c * 50 + 50; ++t2)
        p += sS[t2] * kbase[(size_t)t2 * H + h];       // coalesced 256B rows
    sPart[c][h] = p;
    __syncthreads();
    if (tid < H)
        out[b * H + tid] = (sPart[0][tid] + sPart[1][tid] + sPart[2][tid] + sPart[3][tid]) * inv_l;
}

extern "C" void kernel_launch(void* const* d_in, const int* in_sizes, int n_in,
                              void* d_out, int out_size, void* d_ws, size_t ws_size,
                              hipStream_t stream) {
    const float* q    = (const float*)d_in[0];
    const float* keys = (const float*)d_in[1];
    const int*   lens = (const int*)d_in[2];
    const float* W1   = (const float*)d_in[3];
    const float* b1   = (const float*)d_in[4];
    const float* W2   = (const float*)d_in[5];
    const float* b2   = (const float*)d_in[6];
    const float* Wd   = (const float*)d_in[7];
    const float* bd   = (const float*)d_in[8];
    float* outp = (float*)d_out;

    char* ws = (char*)d_ws;
    __bf16* wsB1 = (__bf16*)(ws + WS_B1);
    __bf16* wsB2 = (__bf16*)(ws + WS_B2);
    float* wsB2v = (float*)(ws + WS_B2V);
    float* wsWdv = (float*)(ws + WS_WDV);
    float* wsQp  = (float*)(ws + WS_QP);

    const bool qws = ws_size >= WS_TOTAL;
    if (qws) {
        prep_all<<<BATCH / 16, 256, 0, stream>>>(q, W1, b1, W2, b2, Wd,
                                                 wsB1, wsB2, wsB2v, wsWdv, wsQp);
        din_main6<true><<<BATCH, 256, 0, stream>>>(q, keys, lens, W1, b1,
                                                   wsB1, wsB2, wsB2v, wsWdv, wsQp, outp);
    } else {
        prep_weights<<<8, 256, 0, stream>>>(W1, W2, b2, Wd, wsB1, wsB2, wsB2v, wsWdv);
        din_main6<false><<<BATCH, 256, 0, stream>>>(q, keys, lens, W1, b1,
                                                    wsB1, wsB2, wsB2v, wsWdv, wsQp, outp);
    }
}

// Round 2
// 429.638 us; speedup vs baseline: 1.2169x; 1.2169x over previous
//
#include <hip/hip_runtime.h>
#include <math.h>

// DIN-style sequence attention, R7.
// R6 post-mortem: __launch_bounds__(256,4) forced VGPR 64 -> B1f[20] (80 regs)
// spilled to scratch (WRITE_SIZE 83->320MB, FETCH 240->717MB), dur 172->297us.
// R7: B1 fragments move to LDS (staged once/block, conflict-free ds_read_b128
// per tile) -- removes both the spill risk and R5's known mid-loop B-frag
// global reloads. Keys 1-deep prefetch kept (now fits: ~110 VGPR under the
// known-good (256,3) cap). LDS 45.5KB -> 3 blocks/CU, same as R5's *measured*
// occupancy, but every wave now holds a 4KB keys tile in flight (MLP fix).

constexpr int BATCH = 4096;
constexpr int T  = 200;
constexpr int H  = 64;     // D_IN = 4H = 256
constexpr int D1 = 80;
constexpr int D2 = 40;
constexpr int MROW = 208;  // 13 M-tiles of 16
constexpr int KS2 = 104;   // sH1 row stride (96+8 pad)

// ws layout (bytes)
constexpr size_t WS_B1  = 0;          // 20 frags * 64 lanes * 16B = 20480
constexpr size_t WS_B2  = 20480;      // 9 frags * 64 lanes * 16B = 9216
constexpr size_t WS_B2V = 29696;      // 48 floats
constexpr size_t WS_WDV = 29888;      // 48 floats
constexpr size_t WS_QP  = 32768;      // 4096*80 floats
constexpr size_t WS_TOTAL = WS_QP + (size_t)BATCH * D1 * 4;

typedef __attribute__((ext_vector_type(8))) __bf16 bf16x8;
typedef __attribute__((ext_vector_type(4))) float  floatx4;

__device__ __forceinline__ float fsig(float x) {
    return __builtin_amdgcn_rcpf(1.0f + __expf(-x));
}
#define MFMA16(a, b, c) __builtin_amdgcn_mfma_f32_16x16x32_bf16((a), (b), (c), 0, 0, 0)

// ---- fragment-ordered bf16 weights (batch-independent), shared body ----
// B1 covers K=128: k<64 -> W1b-W1c ; k>=64 -> W1d row (k-64).
// frag f = n*4+ks; lane (col=lane&15, quad=lane>>4) holds
// B[k=ks*32+quad*8+e][n*16+col].
__device__ __forceinline__ void prep_weights_body(
    int gid, int gstride,
    const float* __restrict__ W1, const float* __restrict__ W2g,
    const float* __restrict__ b2g, const float* __restrict__ Wdg,
    __bf16* __restrict__ wsB1, __bf16* __restrict__ wsB2,
    float* __restrict__ wsB2v, float* __restrict__ wsWdv)
{
    for (int u = gid; u < 20 * 64; u += gstride) {
        const int f = u >> 6, lane = u & 63;
        const int n = f >> 2, ks = f & 3;
        const int col = lane & 15, quad = lane >> 4;
        const int j = n * 16 + col;
        __bf16 frag[8];
        #pragma unroll
        for (int e = 0; e < 8; ++e) {
            const int kk = ks * 32 + quad * 8 + e;
            const float v = (kk < 64)
                ? (W1[(64 + kk) * D1 + j] - W1[(128 + kk) * D1 + j])
                : W1[(128 + kk) * D1 + j];          // (192+(kk-64)) == 128+kk
            frag[e] = (__bf16)v;
        }
        *(bf16x8*)&wsB1[u * 8] = *(bf16x8*)frag;
    }
    for (int u = gid; u < 9 * 64; u += gstride) {
        const int f = u >> 6, lane = u & 63;
        const int n3 = f / 3, ks3 = f % 3;
        const int col = lane & 15, quad = lane >> 4;
        const int j = n3 * 16 + col;
        __bf16 frag[8];
        #pragma unroll
        for (int e = 0; e < 8; ++e) {
            const int kk = ks3 * 32 + quad * 8 + e;
            frag[e] = (j < D2 && kk < D1) ? (__bf16)W2g[kk * D2 + j] : (__bf16)0.f;
        }
        *(bf16x8*)&wsB2[u * 8] = *(bf16x8*)frag;
    }
    if (gid < 48) {
        wsB2v[gid] = (gid < D2) ? b2g[gid] : 0.f;
        wsWdv[gid] = (gid < D2) ? Wdg[gid] : 0.f;
    }
}

// fallback-path standalone weights kernel (ws too small for qpart)
__global__ void prep_weights(const float* __restrict__ W1,
                             const float* __restrict__ W2g,
                             const float* __restrict__ b2g,
                             const float* __restrict__ Wdg,
                             __bf16* __restrict__ wsB1, __bf16* __restrict__ wsB2,
                             float* __restrict__ wsB2v, float* __restrict__ wsWdv)
{
    const int gid = blockIdx.x * 256 + threadIdx.x;
    const int gstride = gridDim.x * 256;
    prep_weights_body(gid, gstride, W1, W2g, b2g, Wdg, wsB1, wsB2, wsB2v, wsWdv);
}

// ---- merged prep: weights (grid-stride) + qpart[b][j] = b1[j] + q_b.(W1a+W1c) ----
__global__ __launch_bounds__(256) void prep_all(
    const float* __restrict__ q_g, const float* __restrict__ W1,
    const float* __restrict__ b1g, const float* __restrict__ W2g,
    const float* __restrict__ b2g, const float* __restrict__ Wdg,
    __bf16* __restrict__ wsB1, __bf16* __restrict__ wsB2,
    float* __restrict__ wsB2v, float* __restrict__ wsWdv,
    float* __restrict__ wsQp)
{
    __shared__ float sW1s[H * D1];   // 20 KB
    __shared__ float sq[16 * H];     // 4 KB
    const int tid = threadIdx.x;
    const int gid = blockIdx.x * 256 + tid;
    const int gstride = gridDim.x * 256;
    prep_weights_body(gid, gstride, W1, W2g, b2g, Wdg, wsB1, wsB2, wsB2v, wsWdv);

    const int b0 = blockIdx.x * 16;
    for (int idx = tid; idx < H * D1; idx += 256) {
        const int i = idx / D1, j = idx % D1;
        sW1s[idx] = W1[i * D1 + j] + W1[(128 + i) * D1 + j];
    }
    for (int idx = tid; idx < 16 * H; idx += 256)
        sq[idx] = q_g[(size_t)b0 * H + idx];
    __syncthreads();
    for (int idx = tid; idx < 16 * D1; idx += 256) {
        const int bl = idx / D1, j = idx % D1;
        float acc = b1g[j];
        #pragma unroll 8
        for (int i = 0; i < H; ++i)
            acc += sq[bl * H + i] * sW1s[i * D1 + j];
        wsQp[(size_t)(b0 + bl) * D1 + j] = acc;
    }
}

// ---- main ----
template<bool QWS>
__global__ __launch_bounds__(256, 3) void din_main7(
    const float* __restrict__ q_g, const float* __restrict__ keys_g,
    const int* __restrict__ len_g, const float* __restrict__ W1,
    const float* __restrict__ b1g,
    const __bf16* __restrict__ wsB1, const __bf16* __restrict__ wsB2,
    const float* __restrict__ wsB2v, const float* __restrict__ wsWdv,
    const float* __restrict__ wsQp, float* __restrict__ out)
{
    __shared__ __align__(16) __bf16 sB1f[20 * 64 * 8];    // 20.5 KB frag-ordered
    __shared__ __align__(16) __bf16 sB2f[9 * 64 * 8];     // 9.2 KB frag-ordered
    __shared__ __align__(16) __bf16 sH1[4][16][KS2];      // 13.3 KB per-wave H1
    __shared__ __align__(16) float sS[MROW];
    __shared__ __align__(16) float sQp[D1];
    __shared__ __align__(16) float sQ[H];                 // fallback only
    __shared__ __align__(16) float sRed[8];
    __shared__ __align__(16) float sPart[4][H];

    const int b    = blockIdx.x;
    const int tid  = threadIdx.x;
    const int lane = tid & 63;
    const int wave = tid >> 6;
    const int quad = lane >> 4;
    const int col  = lane & 15;
    const int len  = len_g[b];
    const float* __restrict__ qrow  = q_g + (size_t)b * H;
    const float* __restrict__ kbase = keys_g + (size_t)b * T * H;

    // ---- stage B1 + B2 frags -> LDS (coalesced float4 copies) ----
    {
        const float4* src1 = (const float4*)wsB1;
        float4* dst1 = (float4*)sB1f;
        for (int idx = tid; idx < 20 * 64; idx += 256) dst1[idx] = src1[idx];
        const float4* src2 = (const float4*)wsB2;
        float4* dst2 = (float4*)sB2f;
        for (int idx = tid; idx < 9 * 64; idx += 256) dst2[idx] = src2[idx];
    }
    if (QWS) { if (tid < D1) sQp[tid] = wsQp[(size_t)b * D1 + tid]; }
    else     { if (tid < H)  sQ[tid]  = qrow[tid]; }

    // per-lane q values for the q*k fragments (quad-broadcast loads)
    const float4 qa0 = *(const float4*)(qrow + quad * 8);
    const float4 qa1 = *(const float4*)(qrow + quad * 8 + 4);
    const float4 qb0 = *(const float4*)(qrow + 32 + quad * 8);
    const float4 qb1 = *(const float4*)(qrow + 32 + quad * 8 + 4);
    float qv[16] = {qa0.x, qa0.y, qa0.z, qa0.w, qa1.x, qa1.y, qa1.z, qa1.w,
                    qb0.x, qb0.y, qb0.z, qb0.w, qb1.x, qb1.y, qb1.z, qb1.w};

    // per-lane layer-2 epilogue constants + qpart values
    float b2v[3], wdv[3], qpv[5];
    #pragma unroll
    for (int n = 0; n < 3; ++n) {
        b2v[n] = wsB2v[n * 16 + col];
        wdv[n] = wsWdv[n * 16 + col];
    }

    // zero own wave's sH1 pad cols 80..95 (wave-local, no barrier needed)
    {
        ushort4 z = {0, 0, 0, 0};
        *(ushort4*)&sH1[wave][lane >> 2][80 + (lane & 3) * 4] = z;
    }
    __syncthreads();   // sB1f + sB2f + sQp (+ sQ) visible

    if (!QWS) {        // inline qpart fallback (ws too small)
        if (tid < D1) {
            float qp = b1g[tid];
            #pragma unroll 8
            for (int i = 0; i < H; ++i)
                qp += sQ[i] * (W1[i * D1 + tid] + W1[(128 + i) * D1 + tid]);
            sQp[tid] = qp;
        }
        __syncthreads();
    }
    #pragma unroll
    for (int n = 0; n < 5; ++n) qpv[n] = sQp[n * 16 + col];

    // ---- Phase B: MFMA scorer; waves stream, no barriers ----
    // 1-deep prefetch: issue next tile's 4x float4 before computing current.
    float4 c0, c1, c2, c3;
    {
        const int rowc = min(wave * 16 + col, T - 1);
        const float* kp = kbase + (size_t)rowc * H + quad * 8;
        c0 = *(const float4*)(kp);
        c1 = *(const float4*)(kp + 4);
        c2 = *(const float4*)(kp + 32);
        c3 = *(const float4*)(kp + 36);
    }
    for (int mt = wave; mt < 13; mt += 4) {
        const int Mb = mt * 16;
        float4 p0 = c0, p1 = c1, p2 = c2, p3 = c3;
        const int mtn = mt + 4;
        if (mtn < 13) {                              // wave-uniform branch
            const int rowc = min(mtn * 16 + col, T - 1);
            const float* kp = kbase + (size_t)rowc * H + quad * 8;
            p0 = *(const float4*)(kp);
            p1 = *(const float4*)(kp + 4);
            p2 = *(const float4*)(kp + 32);
            p3 = *(const float4*)(kp + 36);
        }
        const float kf[16] = {c0.x, c0.y, c0.z, c0.w, c1.x, c1.y, c1.z, c1.w,
                              c2.x, c2.y, c2.z, c2.w, c3.x, c3.y, c3.z, c3.w};
        bf16x8 A0, A1, A2, A3;
        #pragma unroll
        for (int e = 0; e < 8; ++e) {
            A0[e] = (__bf16)kf[e];
            A1[e] = (__bf16)kf[8 + e];
            A2[e] = (__bf16)(qv[e] * kf[e]);          // q*k, k segment 0..31
            A3[e] = (__bf16)(qv[8 + e] * kf[8 + e]);  // q*k, k segment 32..63
        }
        // layer 1: S1 = [k, q*k][16x128] @ W1eff[128x80]; B1 frags from LDS
        #pragma unroll
        for (int n = 0; n < 5; ++n) {
            const bf16x8 Bn0 = *(const bf16x8*)&sB1f[((n * 4 + 0) * 64 + lane) * 8];
            const bf16x8 Bn1 = *(const bf16x8*)&sB1f[((n * 4 + 1) * 64 + lane) * 8];
            const bf16x8 Bn2 = *(const bf16x8*)&sB1f[((n * 4 + 2) * 64 + lane) * 8];
            const bf16x8 Bn3 = *(const bf16x8*)&sB1f[((n * 4 + 3) * 64 + lane) * 8];
            floatx4 acc = {0.f, 0.f, 0.f, 0.f};
            acc = MFMA16(A0, Bn0, acc);
            acc = MFMA16(A1, Bn1, acc);
            acc = MFMA16(A2, Bn2, acc);
            acc = MFMA16(A3, Bn3, acc);
            const float qpn = qpv[n];
            #pragma unroll
            for (int r = 0; r < 4; ++r)               // C/D: row=quad*4+r, col
                sH1[wave][quad * 4 + r][n * 16 + col] = (__bf16)fsig(acc[r] + qpn);
        }
        // layer 2: S2 = H1[16x80] @ W2[80x40]; A from own wave's LDS tile
        const bf16x8 C0 = *(const bf16x8*)&sH1[wave][col][quad * 8];
        const bf16x8 C1 = *(const bf16x8*)&sH1[wave][col][32 + quad * 8];
        const bf16x8 C2 = *(const bf16x8*)&sH1[wave][col][64 + quad * 8];
        float sp0 = 0.f, sp1 = 0.f, sp2 = 0.f, sp3 = 0.f;
        #pragma unroll
        for (int n = 0; n < 3; ++n) {
            floatx4 acc = {0.f, 0.f, 0.f, 0.f};
            #pragma unroll
            for (int ks = 0; ks < 3; ++ks) {          // B2 frags from LDS
                const bf16x8 Bf = *(const bf16x8*)&sB2f[((n * 3 + ks) * 64 + lane) * 8];
                acc = MFMA16(ks == 0 ? C0 : (ks == 1 ? C1 : C2), Bf, acc);
            }
            sp0 += fsig(acc[0] + b2v[n]) * wdv[n];
            sp1 += fsig(acc[1] + b2v[n]) * wdv[n];
            sp2 += fsig(acc[2] + b2v[n]) * wdv[n];
            sp3 += fsig(acc[3] + b2v[n]) * wdv[n];
        }
        #pragma unroll
        for (int off = 1; off <= 8; off <<= 1) {      // reduce 16 cols in quad-group
            sp0 += __shfl_xor(sp0, off, 64);
            sp1 += __shfl_xor(sp1, off, 64);
            sp2 += __shfl_xor(sp2, off, 64);
            sp3 += __shfl_xor(sp3, off, 64);
        }
        if (col == 0) {
            sS[Mb + quad * 4 + 0] = sp0;
            sS[Mb + quad * 4 + 1] = sp1;
            sS[Mb + quad * 4 + 2] = sp2;
            sS[Mb + quad * 4 + 3] = sp3;
        }
        c0 = p0; c1 = p1; c2 = p2; c3 = p3;
    }
    __syncthreads();

    // ---- Phase C: block softmax over T (mask t>=len, scale 1/8) ----
    const int t = tid;
    float score = -INFINITY;
    if (t < T && t < len) score = sS[t] * 0.125f;
    float m = score;
    #pragma unroll
    for (int off = 32; off >= 1; off >>= 1)
        m = fmaxf(m, __shfl_xor(m, off, 64));
    if (lane == 0) sRed[wave] = m;
    __syncthreads();
    m = fmaxf(fmaxf(sRed[0], sRed[1]), fmaxf(sRed[2], sRed[3]));

    float e = 0.0f;
    if (t < T && t < len) e = __expf(score - m);
    float l = e;
    #pragma unroll
    for (int off = 32; off >= 1; off >>= 1)
        l += __shfl_xor(l, off, 64);
    if (lane == 0) sRed[4 + wave] = l;
    if (t < T) sS[t] = e;     // own slot: raw score already consumed here
    __syncthreads();
    l = sRed[4] + sRed[5] + sRed[6] + sRed[7];
    const float inv_l = __builtin_amdgcn_rcpf(l);

    // ---- Phase D: out[b][h] = sum_t w_t * K[t][h] (global fp32, L2-hot) ----
    const int h = tid & 63;
    const int c = tid >> 6;                            // 4 chunks of 50
    float p = 0.0f;
    for (int t2 = c * 50; t2 < c * 50 + 50; ++t2)
        p += sS[t2] * kbase[(size_t)t2 * H + h];       // coalesced 256B rows
    sPart[c][h] = p;
    __syncthreads();
    if (tid < H)
        out[b * H + tid] = (sPart[0][tid] + sPart[1][tid] + sPart[2][tid] + sPart[3][tid]) * inv_l;
}

extern "C" void kernel_launch(void* const* d_in, const int* in_sizes, int n_in,
                              void* d_out, int out_size, void* d_ws, size_t ws_size,
                              hipStream_t stream) {
    const float* q    = (const float*)d_in[0];
    const float* keys = (const float*)d_in[1];
    const int*   lens = (const int*)d_in[2];
    const float* W1   = (const float*)d_in[3];
    const float* b1   = (const float*)d_in[4];
    const float* W2   = (const float*)d_in[5];
    const float* b2   = (const float*)d_in[6];
    const float* Wd   = (const float*)d_in[7];
    const float* bd   = (const float*)d_in[8];
    float* outp = (float*)d_out;

    char* ws = (char*)d_ws;
    __bf16* wsB1 = (__bf16*)(ws + WS_B1);
    __bf16* wsB2 = (__bf16*)(ws + WS_B2);
    float* wsB2v = (float*)(ws + WS_B2V);
    float* wsWdv = (float*)(ws + WS_WDV);
    float* wsQp  = (float*)(ws + WS_QP);

    const bool qws = ws_size >= WS_TOTAL;
    if (qws) {
        prep_all<<<BATCH / 16, 256, 0, stream>>>(q, W1, b1, W2, b2, Wd,
                                                 wsB1, wsB2, wsB2v, wsWdv, wsQp);
        din_main7<true><<<BATCH, 256, 0, stream>>>(q, keys, lens, W1, b1,
                                                   wsB1, wsB2, wsB2v, wsWdv, wsQp, outp);
    } else {
        prep_weights<<<8, 256, 0, stream>>>(W1, W2, b2, Wd, wsB1, wsB2, wsB2v, wsWdv);
        din_main7<false><<<BATCH, 256, 0, stream>>>(q, keys, lens, W1, b1,
                                                    wsB1, wsB2, wsB2v, wsWdv, wsQp, outp);
    }
}

// Round 3
// 360.424 us; speedup vs baseline: 1.4506x; 1.1920x over previous
//
#include <hip/hip_runtime.h>
#include <math.h>

// DIN-style sequence attention, R8.
// R6/R7 post-mortem: __launch_bounds__ 2nd arg caps VGPRs at floor(256/n):
// (256,4)->64, (256,3)->84 (both measured). R5's structure needs ~125 regs
// (B1f 80 + qv 16 + consts 11 + A-frags 16 + addr), so EVERY prior version
// spilled ~20 dwords/thread to scratch (WRITE_SIZE 83-320 MB vs 1 MB output;
// spill reloads in the MFMA loop). R8: (256,2) -> cap 128, and shed 27 cold
// regs (qv/qpv/b2v/wdv move to LDS reads at use) so demand ~124 fits with
// NO spill. VGPR<=128 also lifts occupancy to 4 waves/SIMD (16 waves/CU).
// Pass/fail signal: WRITE_SIZE must drop to ~output size (<10 MB).

constexpr int BATCH = 4096;
constexpr int T  = 200;
constexpr int H  = 64;     // D_IN = 4H = 256
constexpr int D1 = 80;
constexpr int D2 = 40;
constexpr int MROW = 208;  // 13 M-tiles of 16
constexpr int KS2 = 104;   // sH1 row stride (96+8 pad)

// ws layout (bytes)
constexpr size_t WS_B1  = 0;          // 20 frags * 64 lanes * 16B = 20480
constexpr size_t WS_B2  = 20480;      // 9 frags * 64 lanes * 16B = 9216
constexpr size_t WS_B2V = 29696;      // 48 floats
constexpr size_t WS_WDV = 29888;      // 48 floats
constexpr size_t WS_QP  = 32768;      // 4096*80 floats
constexpr size_t WS_TOTAL = WS_QP + (size_t)BATCH * D1 * 4;

typedef __attribute__((ext_vector_type(8))) __bf16 bf16x8;
typedef __attribute__((ext_vector_type(4))) float  floatx4;

__device__ __forceinline__ float fsig(float x) {
    return __builtin_amdgcn_rcpf(1.0f + __expf(-x));
}
#define MFMA16(a, b, c) __builtin_amdgcn_mfma_f32_16x16x32_bf16((a), (b), (c), 0, 0, 0)

// ---- fragment-ordered bf16 weights (batch-independent), shared body ----
// B1 covers K=128: k<64 -> W1b-W1c ; k>=64 -> W1d row (k-64).
// frag f = n*4+ks; lane (col=lane&15, quad=lane>>4) holds
// B[k=ks*32+quad*8+e][n*16+col].
__device__ __forceinline__ void prep_weights_body(
    int gid, int gstride,
    const float* __restrict__ W1, const float* __restrict__ W2g,
    const float* __restrict__ b2g, const float* __restrict__ Wdg,
    __bf16* __restrict__ wsB1, __bf16* __restrict__ wsB2,
    float* __restrict__ wsB2v, float* __restrict__ wsWdv)
{
    for (int u = gid; u < 20 * 64; u += gstride) {
        const int f = u >> 6, lane = u & 63;
        const int n = f >> 2, ks = f & 3;
        const int col = lane & 15, quad = lane >> 4;
        const int j = n * 16 + col;
        __bf16 frag[8];
        #pragma unroll
        for (int e = 0; e < 8; ++e) {
            const int kk = ks * 32 + quad * 8 + e;
            const float v = (kk < 64)
                ? (W1[(64 + kk) * D1 + j] - W1[(128 + kk) * D1 + j])
                : W1[(128 + kk) * D1 + j];          // (192+(kk-64)) == 128+kk
            frag[e] = (__bf16)v;
        }
        *(bf16x8*)&wsB1[u * 8] = *(bf16x8*)frag;
    }
    for (int u = gid; u < 9 * 64; u += gstride) {
        const int f = u >> 6, lane = u & 63;
        const int n3 = f / 3, ks3 = f % 3;
        const int col = lane & 15, quad = lane >> 4;
        const int j = n3 * 16 + col;
        __bf16 frag[8];
        #pragma unroll
        for (int e = 0; e < 8; ++e) {
            const int kk = ks3 * 32 + quad * 8 + e;
            frag[e] = (j < D2 && kk < D1) ? (__bf16)W2g[kk * D2 + j] : (__bf16)0.f;
        }
        *(bf16x8*)&wsB2[u * 8] = *(bf16x8*)frag;
    }
    if (gid < 48) {
        wsB2v[gid] = (gid < D2) ? b2g[gid] : 0.f;
        wsWdv[gid] = (gid < D2) ? Wdg[gid] : 0.f;
    }
}

// fallback-path standalone weights kernel (ws too small for qpart)
__global__ void prep_weights(const float* __restrict__ W1,
                             const float* __restrict__ W2g,
                             const float* __restrict__ b2g,
                             const float* __restrict__ Wdg,
                             __bf16* __restrict__ wsB1, __bf16* __restrict__ wsB2,
                             float* __restrict__ wsB2v, float* __restrict__ wsWdv)
{
    const int gid = blockIdx.x * 256 + threadIdx.x;
    const int gstride = gridDim.x * 256;
    prep_weights_body(gid, gstride, W1, W2g, b2g, Wdg, wsB1, wsB2, wsB2v, wsWdv);
}

// ---- merged prep: weights (grid-stride) + qpart[b][j] = b1[j] + q_b.(W1a+W1c) ----
__global__ __launch_bounds__(256) void prep_all(
    const float* __restrict__ q_g, const float* __restrict__ W1,
    const float* __restrict__ b1g, const float* __restrict__ W2g,
    const float* __restrict__ b2g, const float* __restrict__ Wdg,
    __bf16* __restrict__ wsB1, __bf16* __restrict__ wsB2,
    float* __restrict__ wsB2v, float* __restrict__ wsWdv,
    float* __restrict__ wsQp)
{
    __shared__ float sW1s[H * D1];   // 20 KB
    __shared__ float sq[16 * H];     // 4 KB
    const int tid = threadIdx.x;
    const int gid = blockIdx.x * 256 + tid;
    const int gstride = gridDim.x * 256;
    prep_weights_body(gid, gstride, W1, W2g, b2g, Wdg, wsB1, wsB2, wsB2v, wsWdv);

    const int b0 = blockIdx.x * 16;
    for (int idx = tid; idx < H * D1; idx += 256) {
        const int i = idx / D1, j = idx % D1;
        sW1s[idx] = W1[i * D1 + j] + W1[(128 + i) * D1 + j];
    }
    for (int idx = tid; idx < 16 * H; idx += 256)
        sq[idx] = q_g[(size_t)b0 * H + idx];
    __syncthreads();
    for (int idx = tid; idx < 16 * D1; idx += 256) {
        const int bl = idx / D1, j = idx % D1;
        float acc = b1g[j];
        #pragma unroll 8
        for (int i = 0; i < H; ++i)
            acc += sq[bl * H + i] * sW1s[i * D1 + j];
        wsQp[(size_t)(b0 + bl) * D1 + j] = acc;
    }
}

// ---- main ----
template<bool QWS>
__global__ __launch_bounds__(256, 2) void din_main8(
    const float* __restrict__ q_g, const float* __restrict__ keys_g,
    const int* __restrict__ len_g, const float* __restrict__ W1,
    const float* __restrict__ b1g,
    const __bf16* __restrict__ wsB1, const __bf16* __restrict__ wsB2,
    const float* __restrict__ wsB2v, const float* __restrict__ wsWdv,
    const float* __restrict__ wsQp, float* __restrict__ out)
{
    __shared__ __align__(16) __bf16 sB2f[9 * 64 * 8];     // 9.2 KB frag-ordered
    __shared__ __align__(16) __bf16 sH1[4][16][KS2];      // 13.3 KB per-wave H1
    __shared__ __align__(16) float sS[MROW];
    __shared__ __align__(16) float sQp[D1];
    __shared__ __align__(16) float sQ[H];                 // q row, always staged
    __shared__ __align__(16) float sEpi[2][48];           // b2 / Wd epilogue consts
    __shared__ __align__(16) float sRed[8];
    __shared__ __align__(16) float sPart[4][H];

    const int b    = blockIdx.x;
    const int tid  = threadIdx.x;
    const int lane = tid & 63;
    const int wave = tid >> 6;
    const int quad = lane >> 4;
    const int col  = lane & 15;
    const int len  = len_g[b];
    const float* __restrict__ qrow  = q_g + (size_t)b * H;
    const float* __restrict__ kbase = keys_g + (size_t)b * T * H;

    // ---- stage B2 frags -> LDS (coalesced float4 copy) ----
    {
        const float4* src = (const float4*)wsB2;
        float4* dst = (float4*)sB2f;
        for (int idx = tid; idx < 9 * 64; idx += 256) dst[idx] = src[idx];
    }
    if (tid < H) sQ[tid] = qrow[tid];
    if (tid < 48) {
        sEpi[0][tid] = wsB2v[tid];
        sEpi[1][tid] = wsWdv[tid];
    }
    if (QWS) { if (tid < D1) sQp[tid] = wsQp[(size_t)b * D1 + tid]; }

    // B1 fragments resident in VGPRs (20 x 16B/lane, coalesced, L2-broadcast)
    bf16x8 B1f[20];
    #pragma unroll
    for (int f = 0; f < 20; ++f) B1f[f] = *(const bf16x8*)&wsB1[(f * 64 + lane) * 8];

    // zero own wave's sH1 pad cols 80..95 (wave-local, no barrier needed)
    {
        ushort4 z = {0, 0, 0, 0};
        *(ushort4*)&sH1[wave][lane >> 2][80 + (lane & 3) * 4] = z;
    }
    __syncthreads();   // sB2f + sQ + sEpi + sQp visible

    if (!QWS) {        // inline qpart fallback (ws too small)
        if (tid < D1) {
            float qp = b1g[tid];
            #pragma unroll 8
            for (int i = 0; i < H; ++i)
                qp += sQ[i] * (W1[i * D1 + tid] + W1[(128 + i) * D1 + tid]);
            sQp[tid] = qp;
        }
        __syncthreads();
    }

    // ---- Phase B: MFMA scorer; waves stream, no barriers ----
    for (int mt = wave; mt < 13; mt += 4) {
        const int Mb = mt * 16;
        const int rowc = min(Mb + col, T - 1);       // clamp: tile 12 tail rows
        const float* kp = kbase + (size_t)rowc * H + quad * 8;
        const float4 v0 = *(const float4*)(kp);
        const float4 v1 = *(const float4*)(kp + 4);
        const float4 v2 = *(const float4*)(kp + 32);
        const float4 v3 = *(const float4*)(kp + 36);
        const float kf[16] = {v0.x, v0.y, v0.z, v0.w, v1.x, v1.y, v1.z, v1.w,
                              v2.x, v2.y, v2.z, v2.w, v3.x, v3.y, v3.z, v3.w};
        // per-lane q values from LDS (quad-strided b128 reads, conflict-free)
        const float4 q0 = *(const float4*)&sQ[quad * 8];
        const float4 q1 = *(const float4*)&sQ[quad * 8 + 4];
        const float4 q2 = *(const float4*)&sQ[32 + quad * 8];
        const float4 q3 = *(const float4*)&sQ[32 + quad * 8 + 4];
        const float qf[16] = {q0.x, q0.y, q0.z, q0.w, q1.x, q1.y, q1.z, q1.w,
                              q2.x, q2.y, q2.z, q2.w, q3.x, q3.y, q3.z, q3.w};
        bf16x8 A0, A1, A2, A3;
        #pragma unroll
        for (int e = 0; e < 8; ++e) {
            A0[e] = (__bf16)kf[e];
            A1[e] = (__bf16)kf[8 + e];
            A2[e] = (__bf16)(qf[e] * kf[e]);          // q*k, k segment 0..31
            A3[e] = (__bf16)(qf[8 + e] * kf[8 + e]);  // q*k, k segment 32..63
        }
        // layer 1: S1 = [k, q*k][16x128] @ W1eff[128x80]
        #pragma unroll
        for (int n = 0; n < 5; ++n) {
            floatx4 acc = {0.f, 0.f, 0.f, 0.f};
            acc = MFMA16(A0, B1f[n * 4 + 0], acc);
            acc = MFMA16(A1, B1f[n * 4 + 1], acc);
            acc = MFMA16(A2, B1f[n * 4 + 2], acc);
            acc = MFMA16(A3, B1f[n * 4 + 3], acc);
            const float qpn = sQp[n * 16 + col];      // LDS broadcast, not regs
            #pragma unroll
            for (int r = 0; r < 4; ++r)               // C/D: row=quad*4+r, col
                sH1[wave][quad * 4 + r][n * 16 + col] = (__bf16)fsig(acc[r] + qpn);
        }
        // layer 2: S2 = H1[16x80] @ W2[80x40]; A from own wave's LDS tile
        const bf16x8 C0 = *(const bf16x8*)&sH1[wave][col][quad * 8];
        const bf16x8 C1 = *(const bf16x8*)&sH1[wave][col][32 + quad * 8];
        const bf16x8 C2 = *(const bf16x8*)&sH1[wave][col][64 + quad * 8];
        float sp0 = 0.f, sp1 = 0.f, sp2 = 0.f, sp3 = 0.f;
        #pragma unroll
        for (int n = 0; n < 3; ++n) {
            floatx4 acc = {0.f, 0.f, 0.f, 0.f};
            #pragma unroll
            for (int ks = 0; ks < 3; ++ks) {          // B2 frags from LDS
                const bf16x8 Bf = *(const bf16x8*)&sB2f[((n * 3 + ks) * 64 + lane) * 8];
                acc = MFMA16(ks == 0 ? C0 : (ks == 1 ? C1 : C2), Bf, acc);
            }
            const float b2n = sEpi[0][n * 16 + col];  // LDS broadcast, not regs
            const float wdn = sEpi[1][n * 16 + col];
            sp0 += fsig(acc[0] + b2n) * wdn;
            sp1 += fsig(acc[1] + b2n) * wdn;
            sp2 += fsig(acc[2] + b2n) * wdn;
            sp3 += fsig(acc[3] + b2n) * wdn;
        }
        #pragma unroll
        for (int off = 1; off <= 8; off <<= 1) {      // reduce 16 cols in quad-group
            sp0 += __shfl_xor(sp0, off, 64);
            sp1 += __shfl_xor(sp1, off, 64);
            sp2 += __shfl_xor(sp2, off, 64);
            sp3 += __shfl_xor(sp3, off, 64);
        }
        if (col == 0) {
            sS[Mb + quad * 4 + 0] = sp0;
            sS[Mb + quad * 4 + 1] = sp1;
            sS[Mb + quad * 4 + 2] = sp2;
            sS[Mb + quad * 4 + 3] = sp3;
        }
    }
    __syncthreads();

    // ---- Phase C: block softmax over T (mask t>=len, scale 1/8) ----
    const int t = tid;
    float score = -INFINITY;
    if (t < T && t < len) score = sS[t] * 0.125f;
    float m = score;
    #pragma unroll
    for (int off = 32; off >= 1; off >>= 1)
        m = fmaxf(m, __shfl_xor(m, off, 64));
    if (lane == 0) sRed[wave] = m;
    __syncthreads();
    m = fmaxf(fmaxf(sRed[0], sRed[1]), fmaxf(sRed[2], sRed[3]));

    float e = 0.0f;
    if (t < T && t < len) e = __expf(score - m);
    float l = e;
    #pragma unroll
    for (int off = 32; off >= 1; off >>= 1)
        l += __shfl_xor(l, off, 64);
    if (lane == 0) sRed[4 + wave] = l;
    if (t < T) sS[t] = e;     // own slot: raw score already consumed here
    __syncthreads();
    l = sRed[4] + sRed[5] + sRed[6] + sRed[7];
    const float inv_l = __builtin_amdgcn_rcpf(l);

    // ---- Phase D: out[b][h] = sum_t w_t * K[t][h] (global fp32, L2-hot) ----
    const int h = tid & 63;
    const int c = tid >> 6;                            // 4 chunks of 50
    float p = 0.0f;
    for (int t2 = c * 50; t2 < c * 50 + 50; ++t2)
        p += sS[t2] * kbase[(size_t)t2 * H + h];       // coalesced 256B rows
    sPart[c][h] = p;
    __syncthreads();
    if (tid < H)
        out[b * H + tid] = (sPart[0][tid] + sPart[1][tid] + sPart[2][tid] + sPart[3][tid]) * inv_l;
}

extern "C" void kernel_launch(void* const* d_in, const int* in_sizes, int n_in,
                              void* d_out, int out_size, void* d_ws, size_t ws_size,
                              hipStream_t stream) {
    const float* q    = (const float*)d_in[0];
    const float* keys = (const float*)d_in[1];
    const int*   lens = (const int*)d_in[2];
    const float* W1   = (const float*)d_in[3];
    const float* b1   = (const float*)d_in[4];
    const float* W2   = (const float*)d_in[5];
    const float* b2   = (const float*)d_in[6];
    const float* Wd   = (const float*)d_in[7];
    const float* bd   = (const float*)d_in[8];
    float* outp = (float*)d_out;

    char* ws = (char*)d_ws;
    __bf16* wsB1 = (__bf16*)(ws + WS_B1);
    __bf16* wsB2 = (__bf16*)(ws + WS_B2);
    float* wsB2v = (float*)(ws + WS_B2V);
    float* wsWdv = (float*)(ws + WS_WDV);
    float* wsQp  = (float*)(ws + WS_QP);

    const bool qws = ws_size >= WS_TOTAL;
    if (qws) {
        prep_all<<<BATCH / 16, 256, 0, stream>>>(q, W1, b1, W2, b2, Wd,
                                                 wsB1, wsB2, wsB2v, wsWdv, wsQp);
        din_main8<true><<<BATCH, 256, 0, stream>>>(q, keys, lens, W1, b1,
                                                   wsB1, wsB2, wsB2v, wsWdv, wsQp, outp);
    } else {
        prep_weights<<<8, 256, 0, stream>>>(W1, W2, b2, Wd, wsB1, wsB2, wsB2v, wsWdv);
        din_main8<false><<<BATCH, 256, 0, stream>>>(q, keys, lens, W1, b1,
                                                    wsB1, wsB2, wsB2v, wsWdv, wsQp, outp);
    }
}

// Round 4
// 347.395 us; speedup vs baseline: 1.5050x; 1.0375x over previous
//
#include <hip/hip_runtime.h>
#include <math.h>

// DIN-style sequence attention, R9.
// R8 confirmed: launch_bounds cap was forcing spill all session; (256,2) fixed
// it (WRITE_SIZE 157MB->1MB, dur 172->128us). R9 restructures the math:
//   x.W1 = qpart + k.Beff,  Beff = (W1b-W1c) + diag(q).W1d   [per-batch 64x80]
// Layer-1 is now ONE K=64 matmul: per tile -10 MFMA, -16 muls, -16 cvts, and
// B-frags shrink 80->40 VGPRs, funding the keys 1-deep prefetch (R6's idea,
// now spill-safe under cap 128). prep writes f32 w1bc/w1d tables in frag
// order; each block builds its Beff once (80 fma+cvt per lane).
// Falsifier: WRITE_SIZE must stay ~1 MB (no spill), VGPR <= 128.

constexpr int BATCH = 4096;
constexpr int T  = 200;
constexpr int H  = 64;     // D_IN = 4H = 256
constexpr int D1 = 80;
constexpr int D2 = 40;
constexpr int MROW = 208;  // 13 M-tiles of 16
constexpr int KS2 = 104;   // sH1 row stride (96+8 pad)

// ws layout (bytes)
constexpr size_t WS_B1BC = 0;          // 10 frags * 64 lanes * 8 f32 = 20480
constexpr size_t WS_B1D  = 20480;      // 20480
constexpr size_t WS_B2   = 40960;      // 9 frags * 64 lanes * 8 bf16 = 9216
constexpr size_t WS_B2V  = 50176;      // 48 floats
constexpr size_t WS_WDV  = 50368;      // 48 floats
constexpr size_t WS_QP   = 51200;      // 4096*80 floats
constexpr size_t WS_TOTAL = WS_QP + (size_t)BATCH * D1 * 4;

typedef __attribute__((ext_vector_type(8))) __bf16 bf16x8;
typedef __attribute__((ext_vector_type(4))) float  floatx4;

__device__ __forceinline__ float fsig(float x) {
    return __builtin_amdgcn_rcpf(1.0f + __expf(-x));
}
#define MFMA16(a, b, c) __builtin_amdgcn_mfma_f32_16x16x32_bf16((a), (b), (c), 0, 0, 0)

// ---- weights prep (batch-independent), shared body ----
// Layer-1 tables in frag order, f32: frag f = n*2+ks (ks in {0,1}); lane
// (col=lane&15, quad=lane>>4) holds row k=ks*32+quad*8+e, col j=n*16+col of
//   w1bc[k][j] = W1b[k][j] - W1c[k][j]   and   w1d[k][j] = W1d[k][j].
// B2 frags stay bf16 (frag f = n3*3+ks3 covering K=96 zero-padded).
__device__ __forceinline__ void prep_weights_body(
    int gid, int gstride,
    const float* __restrict__ W1, const float* __restrict__ W2g,
    const float* __restrict__ b2g, const float* __restrict__ Wdg,
    float* __restrict__ wsB1bc, float* __restrict__ wsB1d,
    __bf16* __restrict__ wsB2,
    float* __restrict__ wsB2v, float* __restrict__ wsWdv)
{
    for (int u = gid; u < 10 * 64; u += gstride) {
        const int f = u >> 6, lane = u & 63;
        const int n = f >> 1, ks = f & 1;
        const int col = lane & 15, quad = lane >> 4;
        const int j = n * 16 + col;
        float bcv[8], ddv[8];
        #pragma unroll
        for (int e = 0; e < 8; ++e) {
            const int kk = ks * 32 + quad * 8 + e;
            bcv[e] = W1[(64 + kk) * D1 + j] - W1[(128 + kk) * D1 + j];
            ddv[e] = W1[(192 + kk) * D1 + j];
        }
        *(float4*)&wsB1bc[u * 8]     = *(float4*)&bcv[0];
        *(float4*)&wsB1bc[u * 8 + 4] = *(float4*)&bcv[4];
        *(float4*)&wsB1d[u * 8]      = *(float4*)&ddv[0];
        *(float4*)&wsB1d[u * 8 + 4]  = *(float4*)&ddv[4];
    }
    for (int u = gid; u < 9 * 64; u += gstride) {
        const int f = u >> 6, lane = u & 63;
        const int n3 = f / 3, ks3 = f % 3;
        const int col = lane & 15, quad = lane >> 4;
        const int j = n3 * 16 + col;
        __bf16 frag[8];
        #pragma unroll
        for (int e = 0; e < 8; ++e) {
            const int kk = ks3 * 32 + quad * 8 + e;
            frag[e] = (j < D2 && kk < D1) ? (__bf16)W2g[kk * D2 + j] : (__bf16)0.f;
        }
        *(bf16x8*)&wsB2[u * 8] = *(bf16x8*)frag;
    }
    if (gid < 48) {
        wsB2v[gid] = (gid < D2) ? b2g[gid] : 0.f;
        wsWdv[gid] = (gid < D2) ? Wdg[gid] : 0.f;
    }
}

// fallback-path standalone weights kernel (ws too small for qpart)
__global__ void prep_weights(const float* __restrict__ W1,
                             const float* __restrict__ W2g,
                             const float* __restrict__ b2g,
                             const float* __restrict__ Wdg,
                             float* __restrict__ wsB1bc, float* __restrict__ wsB1d,
                             __bf16* __restrict__ wsB2,
                             float* __restrict__ wsB2v, float* __restrict__ wsWdv)
{
    const int gid = blockIdx.x * 256 + threadIdx.x;
    const int gstride = gridDim.x * 256;
    prep_weights_body(gid, gstride, W1, W2g, b2g, Wdg, wsB1bc, wsB1d, wsB2, wsB2v, wsWdv);
}

// ---- merged prep: weights (grid-stride) + qpart[b][j] = b1[j] + q_b.(W1a+W1c) ----
__global__ __launch_bounds__(256) void prep_all(
    const float* __restrict__ q_g, const float* __restrict__ W1,
    const float* __restrict__ b1g, const float* __restrict__ W2g,
    const float* __restrict__ b2g, const float* __restrict__ Wdg,
    float* __restrict__ wsB1bc, float* __restrict__ wsB1d,
    __bf16* __restrict__ wsB2,
    float* __restrict__ wsB2v, float* __restrict__ wsWdv,
    float* __restrict__ wsQp)
{
    __shared__ float sW1s[H * D1];   // 20 KB
    __shared__ float sq[16 * H];     // 4 KB
    const int tid = threadIdx.x;
    const int gid = blockIdx.x * 256 + tid;
    const int gstride = gridDim.x * 256;
    prep_weights_body(gid, gstride, W1, W2g, b2g, Wdg, wsB1bc, wsB1d, wsB2, wsB2v, wsWdv);

    const int b0 = blockIdx.x * 16;
    for (int idx = tid; idx < H * D1; idx += 256) {
        const int i = idx / D1, j = idx % D1;
        sW1s[idx] = W1[i * D1 + j] + W1[(128 + i) * D1 + j];
    }
    for (int idx = tid; idx < 16 * H; idx += 256)
        sq[idx] = q_g[(size_t)b0 * H + idx];
    __syncthreads();
    for (int idx = tid; idx < 16 * D1; idx += 256) {
        const int bl = idx / D1, j = idx % D1;
        float acc = b1g[j];
        #pragma unroll 8
        for (int i = 0; i < H; ++i)
            acc += sq[bl * H + i] * sW1s[i * D1 + j];
        wsQp[(size_t)(b0 + bl) * D1 + j] = acc;
    }
}

// ---- main ----
template<bool QWS>
__global__ __launch_bounds__(256, 2) void din_main9(
    const float* __restrict__ q_g, const float* __restrict__ keys_g,
    const int* __restrict__ len_g, const float* __restrict__ W1,
    const float* __restrict__ b1g,
    const float* __restrict__ wsB1bc, const float* __restrict__ wsB1d,
    const __bf16* __restrict__ wsB2,
    const float* __restrict__ wsB2v, const float* __restrict__ wsWdv,
    const float* __restrict__ wsQp, float* __restrict__ out)
{
    __shared__ __align__(16) __bf16 sB2f[9 * 64 * 8];     // 9.2 KB frag-ordered
    __shared__ __align__(16) __bf16 sH1[4][16][KS2];      // 13.3 KB per-wave H1
    __shared__ __align__(16) float sS[MROW];
    __shared__ __align__(16) float sQp[D1];
    __shared__ __align__(16) float sQ[H];                 // fallback qpart only
    __shared__ __align__(16) float sEpi[2][48];           // b2 / Wd epilogue consts
    __shared__ __align__(16) float sRed[8];
    __shared__ __align__(16) float sPart[4][H];

    const int b    = blockIdx.x;
    const int tid  = threadIdx.x;
    const int lane = tid & 63;
    const int wave = tid >> 6;
    const int quad = lane >> 4;
    const int col  = lane & 15;
    const int len  = len_g[b];
    const float* __restrict__ qrow  = q_g + (size_t)b * H;
    const float* __restrict__ kbase = keys_g + (size_t)b * T * H;

    // ---- stage B2 frags -> LDS (coalesced float4 copy) ----
    {
        const float4* src = (const float4*)wsB2;
        float4* dst = (float4*)sB2f;
        for (int idx = tid; idx < 9 * 64; idx += 256) dst[idx] = src[idx];
    }
    if (tid < H) sQ[tid] = qrow[tid];
    if (tid < 48) {
        sEpi[0][tid] = wsB2v[tid];
        sEpi[1][tid] = wsWdv[tid];
    }
    if (QWS) { if (tid < D1) sQp[tid] = wsQp[(size_t)b * D1 + tid]; }

    // ---- build per-batch Beff = (W1b - W1c) + diag(q).W1d, frag-ordered ----
    // lane needs q[k] for k = ks*32 + quad*8 + e -> quad-broadcast float4 loads
    bf16x8 Beff[10];
    {
        const float4 qa0 = *(const float4*)(qrow + quad * 8);
        const float4 qa1 = *(const float4*)(qrow + quad * 8 + 4);
        const float4 qb0 = *(const float4*)(qrow + 32 + quad * 8);
        const float4 qb1 = *(const float4*)(qrow + 32 + quad * 8 + 4);
        const float qk[16] = {qa0.x, qa0.y, qa0.z, qa0.w, qa1.x, qa1.y, qa1.z, qa1.w,
                              qb0.x, qb0.y, qb0.z, qb0.w, qb1.x, qb1.y, qb1.z, qb1.w};
        #pragma unroll
        for (int f = 0; f < 10; ++f) {
            const int ks = f & 1;
            const float4 bc0 = *(const float4*)&wsB1bc[(f * 64 + lane) * 8];
            const float4 bc1 = *(const float4*)&wsB1bc[(f * 64 + lane) * 8 + 4];
            const float4 dd0 = *(const float4*)&wsB1d[(f * 64 + lane) * 8];
            const float4 dd1 = *(const float4*)&wsB1d[(f * 64 + lane) * 8 + 4];
            const float bcv[8] = {bc0.x, bc0.y, bc0.z, bc0.w, bc1.x, bc1.y, bc1.z, bc1.w};
            const float ddv[8] = {dd0.x, dd0.y, dd0.z, dd0.w, dd1.x, dd1.y, dd1.z, dd1.w};
            #pragma unroll
            for (int e = 0; e < 8; ++e)
                Beff[f][e] = (__bf16)(bcv[e] + qk[ks * 8 + e] * ddv[e]);
        }
    }

    // zero own wave's sH1 pad cols 80..95 (wave-local, no barrier needed)
    {
        ushort4 z = {0, 0, 0, 0};
        *(ushort4*)&sH1[wave][lane >> 2][80 + (lane & 3) * 4] = z;
    }
    __syncthreads();   // sB2f + sQ + sEpi + sQp visible

    if (!QWS) {        // inline qpart fallback (ws too small)
        if (tid < D1) {
            float qp = b1g[tid];
            #pragma unroll 8
            for (int i = 0; i < H; ++i)
                qp += sQ[i] * (W1[i * D1 + tid] + W1[(128 + i) * D1 + tid]);
            sQp[tid] = qp;
        }
        __syncthreads();
    }

    // ---- Phase B: MFMA scorer; waves stream, no barriers ----
    // 1-deep prefetch: next tile's 4x float4 issued before computing current.
    float4 c0, c1, c2, c3;
    {
        const int rowc = min(wave * 16 + col, T - 1);
        const float* kp = kbase + (size_t)rowc * H + quad * 8;
        c0 = *(const float4*)(kp);
        c1 = *(const float4*)(kp + 4);
        c2 = *(const float4*)(kp + 32);
        c3 = *(const float4*)(kp + 36);
    }
    for (int mt = wave; mt < 13; mt += 4) {
        const int Mb = mt * 16;
        float4 p0 = c0, p1 = c1, p2 = c2, p3 = c3;
        const int mtn = mt + 4;
        if (mtn < 13) {                              // wave-uniform branch
            const int rowc = min(mtn * 16 + col, T - 1);
            const float* kp = kbase + (size_t)rowc * H + quad * 8;
            p0 = *(const float4*)(kp);
            p1 = *(const float4*)(kp + 4);
            p2 = *(const float4*)(kp + 32);
            p3 = *(const float4*)(kp + 36);
        }
        const float kf[16] = {c0.x, c0.y, c0.z, c0.w, c1.x, c1.y, c1.z, c1.w,
                              c2.x, c2.y, c2.z, c2.w, c3.x, c3.y, c3.z, c3.w};
        bf16x8 A0, A1;
        #pragma unroll
        for (int e = 0; e < 8; ++e) {
            A0[e] = (__bf16)kf[e];                    // k segment 0..31
            A1[e] = (__bf16)kf[8 + e];                // k segment 32..63
        }
        // layer 1: S1 = k[16x64] @ Beff[64x80] (+ qpart), single K=64 matmul
        #pragma unroll
        for (int n = 0; n < 5; ++n) {
            floatx4 acc = {0.f, 0.f, 0.f, 0.f};
            acc = MFMA16(A0, Beff[n * 2 + 0], acc);
            acc = MFMA16(A1, Beff[n * 2 + 1], acc);
            const float qpn = sQp[n * 16 + col];      // LDS broadcast
            #pragma unroll
            for (int r = 0; r < 4; ++r)               // C/D: row=quad*4+r, col
                sH1[wave][quad * 4 + r][n * 16 + col] = (__bf16)fsig(acc[r] + qpn);
        }
        // layer 2: S2 = H1[16x80] @ W2[80x40]; A from own wave's LDS tile
        const bf16x8 C0 = *(const bf16x8*)&sH1[wave][col][quad * 8];
        const bf16x8 C1 = *(const bf16x8*)&sH1[wave][col][32 + quad * 8];
        const bf16x8 C2 = *(const bf16x8*)&sH1[wave][col][64 + quad * 8];
        float sp0 = 0.f, sp1 = 0.f, sp2 = 0.f, sp3 = 0.f;
        #pragma unroll
        for (int n = 0; n < 3; ++n) {
            floatx4 acc = {0.f, 0.f, 0.f, 0.f};
            #pragma unroll
            for (int ks = 0; ks < 3; ++ks) {          // B2 frags from LDS
                const bf16x8 Bf = *(const bf16x8*)&sB2f[((n * 3 + ks) * 64 + lane) * 8];
                acc = MFMA16(ks == 0 ? C0 : (ks == 1 ? C1 : C2), Bf, acc);
            }
            const float b2n = sEpi[0][n * 16 + col];  // LDS broadcast
            const float wdn = sEpi[1][n * 16 + col];
            sp0 += fsig(acc[0] + b2n) * wdn;
            sp1 += fsig(acc[1] + b2n) * wdn;
            sp2 += fsig(acc[2] + b2n) * wdn;
            sp3 += fsig(acc[3] + b2n) * wdn;
        }
        #pragma unroll
        for (int off = 1; off <= 8; off <<= 1) {      // reduce 16 cols in quad-group
            sp0 += __shfl_xor(sp0, off, 64);
            sp1 += __shfl_xor(sp1, off, 64);
            sp2 += __shfl_xor(sp2, off, 64);
            sp3 += __shfl_xor(sp3, off, 64);
        }
        if (col == 0) {
            sS[Mb + quad * 4 + 0] = sp0;
            sS[Mb + quad * 4 + 1] = sp1;
            sS[Mb + quad * 4 + 2] = sp2;
            sS[Mb + quad * 4 + 3] = sp3;
        }
        c0 = p0; c1 = p1; c2 = p2; c3 = p3;
    }
    __syncthreads();

    // ---- Phase C: block softmax over T (mask t>=len, scale 1/8) ----
    const int t = tid;
    float score = -INFINITY;
    if (t < T && t < len) score = sS[t] * 0.125f;
    float m = score;
    #pragma unroll
    for (int off = 32; off >= 1; off >>= 1)
        m = fmaxf(m, __shfl_xor(m, off, 64));
    if (lane == 0) sRed[wave] = m;
    __syncthreads();
    m = fmaxf(fmaxf(sRed[0], sRed[1]), fmaxf(sRed[2], sRed[3]));

    float e = 0.0f;
    if (t < T && t < len) e = __expf(score - m);
    float l = e;
    #pragma unroll
    for (int off = 32; off >= 1; off >>= 1)
        l += __shfl_xor(l, off, 64);
    if (lane == 0) sRed[4 + wave] = l;
    if (t < T) sS[t] = e;     // own slot: raw score already consumed here
    __syncthreads();
    l = sRed[4] + sRed[5] + sRed[6] + sRed[7];
    const float inv_l = __builtin_amdgcn_rcpf(l);

    // ---- Phase D: out[b][h] = sum_t w_t * K[t][h] (global fp32, L2-hot) ----
    const int h = tid & 63;
    const int c = tid >> 6;                            // 4 chunks of 50
    float p = 0.0f;
    for (int t2 = c * 50; t2 < c * 50 + 50; ++t2)
        p += sS[t2] * kbase[(size_t)t2 * H + h];       // coalesced 256B rows
    sPart[c][h] = p;
    __syncthreads();
    if (tid < H)
        out[b * H + tid] = (sPart[0][tid] + sPart[1][tid] + sPart[2][tid] + sPart[3][tid]) * inv_l;
}

extern "C" void kernel_launch(void* const* d_in, const int* in_sizes, int n_in,
                              void* d_out, int out_size, void* d_ws, size_t ws_size,
                              hipStream_t stream) {
    const float* q    = (const float*)d_in[0];
    const float* keys = (const float*)d_in[1];
    const int*   lens = (const int*)d_in[2];
    const float* W1   = (const float*)d_in[3];
    const float* b1   = (const float*)d_in[4];
    const float* W2   = (const float*)d_in[5];
    const float* b2   = (const float*)d_in[6];
    const float* Wd   = (const float*)d_in[7];
    const float* bd   = (const float*)d_in[8];
    float* outp = (float*)d_out;

    char* ws = (char*)d_ws;
    float*  wsB1bc = (float*)(ws + WS_B1BC);
    float*  wsB1d  = (float*)(ws + WS_B1D);
    __bf16* wsB2   = (__bf16*)(ws + WS_B2);
    float*  wsB2v  = (float*)(ws + WS_B2V);
    float*  wsWdv  = (float*)(ws + WS_WDV);
    float*  wsQp   = (float*)(ws + WS_QP);

    const bool qws = ws_size >= WS_TOTAL;
    if (qws) {
        prep_all<<<BATCH / 16, 256, 0, stream>>>(q, W1, b1, W2, b2, Wd,
                                                 wsB1bc, wsB1d, wsB2, wsB2v, wsWdv, wsQp);
        din_main9<true><<<BATCH, 256, 0, stream>>>(q, keys, lens, W1, b1,
                                                   wsB1bc, wsB1d, wsB2, wsB2v, wsWdv,
                                                   wsQp, outp);
    } else {
        prep_weights<<<8, 256, 0, stream>>>(W1, W2, b2, Wd,
                                            wsB1bc, wsB1d, wsB2, wsB2v, wsWdv);
        din_main9<false><<<BATCH, 256, 0, stream>>>(q, keys, lens, W1, b1,
                                                    wsB1bc, wsB1d, wsB2, wsB2v, wsWdv,
                                                    wsQp, outp);
    }
}

// Round 6
// 327.628 us; speedup vs baseline: 1.5959x; 1.0603x over previous
//
#include <hip/hip_runtime.h>
#include <math.h>

// DIN-style sequence attention, R10b (identical to R10; prior bench died to
// an infra container failure with no counters — audited for OOB/hang/scratch,
// none found; resubmitting unchanged per one-variable-at-a-time discipline).
// R9 post-mortem: removing MFMAs/VALU barely helped -> per-tile LATENCY CHAIN
// is the wall (load->cvt->MFMA->sig->LDS rt->MFMA->sig->4xshfl), occupancy
// hard-capped at 4 waves/SIMD by the launch_bounds cap rule (cap=256/n).
// R10: 2x ILP per wave -- process tile pairs (mt, mt+4) with interleaved
// layer-1 (sharing each Beff/B2 fragment read), stash B's sigmoids in regs
// during A's layer-2, replay layer-2 for B. Beff moves to LDS (built once
// per block) to fund the pair state under the 128-reg cap. prep_all deleted:
// qpart computed in-block from precomputed W1a+W1c table (prep_weights only).
// Falsifiers: WRITE_SIZE ~1MB (no spill), VGPR<=128, total -> ~300-315.

constexpr int BATCH = 4096;
constexpr int T  = 200;
constexpr int H  = 64;     // D_IN = 4H = 256
constexpr int D1 = 80;
constexpr int D2 = 40;
constexpr int MROW = 208;  // 13 M-tiles of 16
constexpr int KS2 = 104;   // sH1 row stride (96+8 pad)

// ws layout (bytes)
constexpr size_t WS_B1BC = 0;          // 10 frags * 64 lanes * 8 f32 = 20480
constexpr size_t WS_B1D  = 20480;      // 20480
constexpr size_t WS_B2   = 40960;      // 9 frags * 64 lanes * 8 bf16 = 9216
constexpr size_t WS_B2V  = 50176;      // 48 floats
constexpr size_t WS_WDV  = 50368;      // 48 floats
constexpr size_t WS_W1S  = 50560;      // 64*80 f32 = 20480 (W1a + W1c)
constexpr size_t WS_TOTAL= 71040;

typedef __attribute__((ext_vector_type(8))) __bf16 bf16x8;
typedef __attribute__((ext_vector_type(4))) float  floatx4;

__device__ __forceinline__ float fsig(float x) {
    return __builtin_amdgcn_rcpf(1.0f + __expf(-x));
}
#define MFMA16(a, b, c) __builtin_amdgcn_mfma_f32_16x16x32_bf16((a), (b), (c), 0, 0, 0)

// ---- single prep kernel (batch-independent tables, grid-stride) ----
// Layer-1 tables frag-ordered f32: frag f = n*2+ks; lane (col=lane&15,
// quad=lane>>4) holds row k=ks*32+quad*8+e, col j=n*16+col of
//   w1bc = W1b - W1c   and   w1d = W1d.
// B2 frags bf16 (f = n3*3+ks3, K=96 zero-padded). W1s = W1a + W1c (row-major).
__global__ void prep_weights(const float* __restrict__ W1,
                             const float* __restrict__ W2g,
                             const float* __restrict__ b2g,
                             const float* __restrict__ Wdg,
                             float* __restrict__ wsB1bc, float* __restrict__ wsB1d,
                             __bf16* __restrict__ wsB2,
                             float* __restrict__ wsB2v, float* __restrict__ wsWdv,
                             float* __restrict__ wsW1s)
{
    const int gid = blockIdx.x * 256 + threadIdx.x;
    const int gstride = gridDim.x * 256;
    for (int u = gid; u < 10 * 64; u += gstride) {
        const int f = u >> 6, lane = u & 63;
        const int n = f >> 1, ks = f & 1;
        const int col = lane & 15, quad = lane >> 4;
        const int j = n * 16 + col;
        float bcv[8], ddv[8];
        #pragma unroll
        for (int e = 0; e < 8; ++e) {
            const int kk = ks * 32 + quad * 8 + e;
            bcv[e] = W1[(64 + kk) * D1 + j] - W1[(128 + kk) * D1 + j];
            ddv[e] = W1[(192 + kk) * D1 + j];
        }
        *(float4*)&wsB1bc[u * 8]     = *(float4*)&bcv[0];
        *(float4*)&wsB1bc[u * 8 + 4] = *(float4*)&bcv[4];
        *(float4*)&wsB1d[u * 8]      = *(float4*)&ddv[0];
        *(float4*)&wsB1d[u * 8 + 4]  = *(float4*)&ddv[4];
    }
    for (int u = gid; u < 9 * 64; u += gstride) {
        const int f = u >> 6, lane = u & 63;
        const int n3 = f / 3, ks3 = f % 3;
        const int col = lane & 15, quad = lane >> 4;
        const int j = n3 * 16 + col;
        __bf16 frag[8];
        #pragma unroll
        for (int e = 0; e < 8; ++e) {
            const int kk = ks3 * 32 + quad * 8 + e;
            frag[e] = (j < D2 && kk < D1) ? (__bf16)W2g[kk * D2 + j] : (__bf16)0.f;
        }
        *(bf16x8*)&wsB2[u * 8] = *(bf16x8*)frag;
    }
    for (int idx = gid; idx < H * D1; idx += gstride)
        wsW1s[idx] = W1[idx] + W1[128 * D1 + idx];
    if (gid < 48) {
        wsB2v[gid] = (gid < D2) ? b2g[gid] : 0.f;
        wsWdv[gid] = (gid < D2) ? Wdg[gid] : 0.f;
    }
}

// ---- main ----
__global__ __launch_bounds__(256, 2) void din_main10(
    const float* __restrict__ q_g, const float* __restrict__ keys_g,
    const int* __restrict__ len_g, const float* __restrict__ b1g,
    const float* __restrict__ wsB1bc, const float* __restrict__ wsB1d,
    const __bf16* __restrict__ wsB2,
    const float* __restrict__ wsB2v, const float* __restrict__ wsWdv,
    const float* __restrict__ wsW1s, float* __restrict__ out)
{
    __shared__ __align__(16) __bf16 sBef[10 * 64 * 8];    // 10.0 KB Beff frags
    __shared__ __align__(16) __bf16 sB2f[9 * 64 * 8];     // 9.2 KB B2 frags
    __shared__ __align__(16) __bf16 sH1[4][16][KS2];      // 13.3 KB per-wave H1
    __shared__ __align__(16) float sS[MROW];
    __shared__ __align__(16) float sQp[D1];
    __shared__ __align__(16) float sQpP[4][D1];           // qpart partials
    __shared__ __align__(16) float sEpi[2][48];
    __shared__ __align__(16) float sRed[8];
    __shared__ __align__(16) float sPart[4][H];

    const int b    = blockIdx.x;
    const int tid  = threadIdx.x;
    const int lane = tid & 63;
    const int wave = tid >> 6;
    const int quad = lane >> 4;
    const int col  = lane & 15;
    const int len  = len_g[b];
    const float* __restrict__ qrow  = q_g + (size_t)b * H;
    const float* __restrict__ kbase = keys_g + (size_t)b * T * H;

    // ---- stage B2 frags -> LDS ----
    {
        const float4* src = (const float4*)wsB2;
        float4* dst = (float4*)sB2f;
        for (int idx = tid; idx < 9 * 64; idx += 256) dst[idx] = src[idx];
    }
    if (tid < 48) {
        sEpi[0][tid] = wsB2v[tid];
        sEpi[1][tid] = wsWdv[tid];
    }

    // ---- build Beff = (W1b - W1c) + diag(q).W1d into LDS, frag-ordered ----
    for (int u = tid; u < 10 * 64; u += 256) {
        const int f = u >> 6, ln = u & 63;
        const int ks = f & 1, qd = ln >> 4;
        const float4 bc0 = *(const float4*)&wsB1bc[u * 8];
        const float4 bc1 = *(const float4*)&wsB1bc[u * 8 + 4];
        const float4 dd0 = *(const float4*)&wsB1d[u * 8];
        const float4 dd1 = *(const float4*)&wsB1d[u * 8 + 4];
        const float4 q0 = *(const float4*)(qrow + ks * 32 + qd * 8);
        const float4 q1 = *(const float4*)(qrow + ks * 32 + qd * 8 + 4);
        __bf16 fr[8];
        fr[0] = (__bf16)(bc0.x + q0.x * dd0.x);
        fr[1] = (__bf16)(bc0.y + q0.y * dd0.y);
        fr[2] = (__bf16)(bc0.z + q0.z * dd0.z);
        fr[3] = (__bf16)(bc0.w + q0.w * dd0.w);
        fr[4] = (__bf16)(bc1.x + q1.x * dd1.x);
        fr[5] = (__bf16)(bc1.y + q1.y * dd1.y);
        fr[6] = (__bf16)(bc1.z + q1.z * dd1.z);
        fr[7] = (__bf16)(bc1.w + q1.w * dd1.w);
        *(bf16x8*)&sBef[u * 8] = *(bf16x8*)fr;
    }

    // ---- qpart partials: wave w covers i in [16w, 16w+16), cols j=lane / 64+col ----
    {
        const int j2 = 64 + col;
        float qp0 = (wave == 0) ? b1g[lane] : 0.f;
        float qp1 = (wave == 0) ? b1g[j2]   : 0.f;
        const int i0 = wave * 16;
        #pragma unroll
        for (int ii = 0; ii < 16; ++ii) {
            const int i = i0 + ii;
            const float qi = qrow[i];
            qp0 += qi * wsW1s[i * D1 + lane];
            qp1 += qi * wsW1s[i * D1 + j2];
        }
        sQpP[wave][lane] = qp0;
        if (lane < 16) sQpP[wave][j2] = qp1;
    }

    // zero own wave's sH1 pad cols 80..95 (wave-local)
    {
        ushort4 z = {0, 0, 0, 0};
        *(ushort4*)&sH1[wave][lane >> 2][80 + (lane & 3) * 4] = z;
    }
    __syncthreads();   // sBef + sB2f + sEpi + sQpP visible
    if (tid < D1)
        sQp[tid] = sQpP[0][tid] + sQpP[1][tid] + sQpP[2][tid] + sQpP[3][tid];
    __syncthreads();   // sQp visible

    // ---- Phase B: paired-tile MFMA scorer; waves stream, no barriers ----
    auto loadA = [&](int mt, bf16x8& A0, bf16x8& A1) {
        const int rowc = min(mt * 16 + col, T - 1);
        const float* kp = kbase + (size_t)rowc * H + quad * 8;
        const float4 v0 = *(const float4*)(kp);
        const float4 v1 = *(const float4*)(kp + 4);
        const float4 v2 = *(const float4*)(kp + 32);
        const float4 v3 = *(const float4*)(kp + 36);
        A0[0] = (__bf16)v0.x; A0[1] = (__bf16)v0.y; A0[2] = (__bf16)v0.z; A0[3] = (__bf16)v0.w;
        A0[4] = (__bf16)v1.x; A0[5] = (__bf16)v1.y; A0[6] = (__bf16)v1.z; A0[7] = (__bf16)v1.w;
        A1[0] = (__bf16)v2.x; A1[1] = (__bf16)v2.y; A1[2] = (__bf16)v2.z; A1[3] = (__bf16)v2.w;
        A1[4] = (__bf16)v3.x; A1[5] = (__bf16)v3.y; A1[6] = (__bf16)v3.z; A1[7] = (__bf16)v3.w;
    };
    auto layer2body = [&]() -> floatx4 {
        const bf16x8 C0 = *(const bf16x8*)&sH1[wave][col][quad * 8];
        const bf16x8 C1 = *(const bf16x8*)&sH1[wave][col][32 + quad * 8];
        const bf16x8 C2 = *(const bf16x8*)&sH1[wave][col][64 + quad * 8];
        floatx4 sp = {0.f, 0.f, 0.f, 0.f};
        #pragma unroll
        for (int n = 0; n < 3; ++n) {
            floatx4 acc = {0.f, 0.f, 0.f, 0.f};
            acc = MFMA16(C0, *(const bf16x8*)&sB2f[((n * 3 + 0) * 64 + lane) * 8], acc);
            acc = MFMA16(C1, *(const bf16x8*)&sB2f[((n * 3 + 1) * 64 + lane) * 8], acc);
            acc = MFMA16(C2, *(const bf16x8*)&sB2f[((n * 3 + 2) * 64 + lane) * 8], acc);
            const float b2n = sEpi[0][n * 16 + col];
            const float wdn = sEpi[1][n * 16 + col];
            sp[0] += fsig(acc[0] + b2n) * wdn;
            sp[1] += fsig(acc[1] + b2n) * wdn;
            sp[2] += fsig(acc[2] + b2n) * wdn;
            sp[3] += fsig(acc[3] + b2n) * wdn;
        }
        return sp;
    };
    auto tilePair = [&](int mtA, int mtB, bool hasB) {
        bf16x8 A0a, A1a, A0b, A1b;
        loadA(mtA, A0a, A1a);
        if (hasB) loadA(mtB, A0b, A1b);
        __bf16 hB[20];
        // layer 1 interleaved: Beff frag read once, used by both tiles
        #pragma unroll
        for (int n = 0; n < 5; ++n) {
            const bf16x8 Bn0 = *(const bf16x8*)&sBef[((n * 2 + 0) * 64 + lane) * 8];
            const bf16x8 Bn1 = *(const bf16x8*)&sBef[((n * 2 + 1) * 64 + lane) * 8];
            floatx4 aA = {0.f, 0.f, 0.f, 0.f};
            aA = MFMA16(A0a, Bn0, aA);
            aA = MFMA16(A1a, Bn1, aA);
            floatx4 aB = {0.f, 0.f, 0.f, 0.f};
            if (hasB) {
                aB = MFMA16(A0b, Bn0, aB);
                aB = MFMA16(A1b, Bn1, aB);
            }
            const float qpn = sQp[n * 16 + col];
            #pragma unroll
            for (int r = 0; r < 4; ++r)               // C/D: row=quad*4+r, col
                sH1[wave][quad * 4 + r][n * 16 + col] = (__bf16)fsig(aA[r] + qpn);
            if (hasB) {
                #pragma unroll
                for (int r = 0; r < 4; ++r)
                    hB[n * 4 + r] = (__bf16)fsig(aB[r] + qpn);   // stash (10 regs)
            }
        }
        // layer 2 for A (C-reads then MFMAs; same-wave DS is in-order, and
        // aliasing on sH1 pins program order of the B-writes below after them)
        const floatx4 spA = layer2body();
        if (hasB) {
            #pragma unroll
            for (int n = 0; n < 5; ++n)
                #pragma unroll
                for (int r = 0; r < 4; ++r)
                    sH1[wave][quad * 4 + r][n * 16 + col] = hB[n * 4 + r];
        }
        floatx4 spB = {0.f, 0.f, 0.f, 0.f};
        if (hasB) spB = layer2body();
        // quad-group reduce across 16 cols (A and B chains ILP'd)
        float s0 = spA[0], s1 = spA[1], s2 = spA[2], s3 = spA[3];
        float t0 = spB[0], t1 = spB[1], t2 = spB[2], t3 = spB[3];
        #pragma unroll
        for (int off = 1; off <= 8; off <<= 1) {
            s0 += __shfl_xor(s0, off, 64);
            s1 += __shfl_xor(s1, off, 64);
            s2 += __shfl_xor(s2, off, 64);
            s3 += __shfl_xor(s3, off, 64);
            if (hasB) {
                t0 += __shfl_xor(t0, off, 64);
                t1 += __shfl_xor(t1, off, 64);
                t2 += __shfl_xor(t2, off, 64);
                t3 += __shfl_xor(t3, off, 64);
            }
        }
        if (col == 0) {
            sS[mtA * 16 + quad * 4 + 0] = s0;
            sS[mtA * 16 + quad * 4 + 1] = s1;
            sS[mtA * 16 + quad * 4 + 2] = s2;
            sS[mtA * 16 + quad * 4 + 3] = s3;
            if (hasB) {
                sS[mtB * 16 + quad * 4 + 0] = t0;
                sS[mtB * 16 + quad * 4 + 1] = t1;
                sS[mtB * 16 + quad * 4 + 2] = t2;
                sS[mtB * 16 + quad * 4 + 3] = t3;
            }
        }
    };

    tilePair(wave, wave + 4, true);            // tiles 0..7
    if (wave == 0) tilePair(8, 12, true);      // tiles 8,12
    else           tilePair(wave + 8, 0, false); // tiles 9,10,11
    __syncthreads();

    // ---- Phase C: block softmax over T (mask t>=len, scale 1/8) ----
    const int t = tid;
    float score = -INFINITY;
    if (t < T && t < len) score = sS[t] * 0.125f;
    float m = score;
    #pragma unroll
    for (int off = 32; off >= 1; off >>= 1)
        m = fmaxf(m, __shfl_xor(m, off, 64));
    if (lane == 0) sRed[wave] = m;
    __syncthreads();
    m = fmaxf(fmaxf(sRed[0], sRed[1]), fmaxf(sRed[2], sRed[3]));

    float e = 0.0f;
    if (t < T && t < len) e = __expf(score - m);
    float l = e;
    #pragma unroll
    for (int off = 32; off >= 1; off >>= 1)
        l += __shfl_xor(l, off, 64);
    if (lane == 0) sRed[4 + wave] = l;
    if (t < T) sS[t] = e;
    __syncthreads();
    l = sRed[4] + sRed[5] + sRed[6] + sRed[7];
    const float inv_l = __builtin_amdgcn_rcpf(l);

    // ---- Phase D: out[b][h] = sum_t w_t * K[t][h] (global fp32, L2-hot) ----
    const int h = tid & 63;
    const int c = tid >> 6;                            // 4 chunks of 50
    float p = 0.0f;
    for (int t2 = c * 50; t2 < c * 50 + 50; ++t2)
        p += sS[t2] * kbase[(size_t)t2 * H + h];
    sPart[c][h] = p;
    __syncthreads();
    if (tid < H)
        out[b * H + tid] = (sPart[0][tid] + sPart[1][tid] + sPart[2][tid] + sPart[3][tid]) * inv_l;
}

extern "C" void kernel_launch(void* const* d_in, const int* in_sizes, int n_in,
                              void* d_out, int out_size, void* d_ws, size_t ws_size,
                              hipStream_t stream) {
    const float* q    = (const float*)d_in[0];
    const float* keys = (const float*)d_in[1];
    const int*   lens = (const int*)d_in[2];
    const float* W1   = (const float*)d_in[3];
    const float* b1   = (const float*)d_in[4];
    const float* W2   = (const float*)d_in[5];
    const float* b2   = (const float*)d_in[6];
    const float* Wd   = (const float*)d_in[7];
    const float* bd   = (const float*)d_in[8];
    float* outp = (float*)d_out;

    char* ws = (char*)d_ws;
    float*  wsB1bc = (float*)(ws + WS_B1BC);
    float*  wsB1d  = (float*)(ws + WS_B1D);
    __bf16* wsB2   = (__bf16*)(ws + WS_B2);
    float*  wsB2v  = (float*)(ws + WS_B2V);
    float*  wsWdv  = (float*)(ws + WS_WDV);
    float*  wsW1s  = (float*)(ws + WS_W1S);

    prep_weights<<<16, 256, 0, stream>>>(W1, W2, b2, Wd,
                                         wsB1bc, wsB1d, wsB2, wsB2v, wsWdv, wsW1s);
    din_main10<<<BATCH, 256, 0, stream>>>(q, keys, lens, b1,
                                          wsB1bc, wsB1d, wsB2, wsB2v, wsWdv,
                                          wsW1s, outp);
}